// Round 11
// baseline (175.764 us; speedup 1.0000x reference)
//
#include <hip/hip_runtime.h>

#define Bq 8
#define Sq 1024
#define Dq 512

typedef __attribute__((ext_vector_type(8))) short bf16x8;
typedef __attribute__((ext_vector_type(4))) float f32x4;

__device__ __forceinline__ unsigned short f2bf(float f) {
  unsigned int u = __float_as_uint(f);
  return (unsigned short)((u + 0x7fffu + ((u >> 16) & 1u)) >> 16);
}

__device__ __forceinline__ void load_lds16(const unsigned short* g, unsigned short* l) {
  __builtin_amdgcn_global_load_lds(
      (const __attribute__((address_space(1))) unsigned int*)g,
      (__attribute__((address_space(3))) unsigned int*)l, 16, 0, 0);
}

// ---- prep_inp: transpose to inpT (bf16) + race-free colsum partials ----
__global__ void prep_inp(const float* __restrict__ inp, unsigned short* __restrict__ inpT,
                         float* __restrict__ partial) {
  __shared__ unsigned short tile[32][33];
  __shared__ float csum[8][33];
  int b = blockIdx.x;
  int t0 = blockIdx.y * 32, d0 = blockIdx.z * 32;
  int tx = threadIdx.x, ty = threadIdx.y;
  const float* src = inp + ((size_t)b * Sq + t0) * Dq + d0;
  float part = 0.f;
#pragma unroll
  for (int i = 0; i < 4; ++i) {
    float v = src[(size_t)(ty + i * 8) * Dq + tx];
    tile[ty + i * 8][tx] = f2bf(v);
    part += v;
  }
  csum[ty][tx] = part;
  __syncthreads();
  unsigned short* dst = inpT + (size_t)b * Dq * Sq;
#pragma unroll
  for (int i = 0; i < 4; ++i)
    dst[(size_t)(d0 + ty + i * 8) * Sq + t0 + tx] = tile[tx][ty + i * 8];
  if (ty == 0) {
    float s = 0.f;
#pragma unroll
    for (int i = 0; i < 8; ++i) s += csum[i][tx];
    partial[((size_t)b * 32 + blockIdx.y) * Dq + d0 + tx] = s;
  }
}

// ---- prep_asp: 16 rows/block; colsum reduced ONCE per block into LDS;
// exact fp32 fac; asp bf16 cast; blocks >=512 convert w1/w2 ----
__global__ __launch_bounds__(256) void prep_asp(
    const float* __restrict__ aspect, const float* __restrict__ partial,
    const float* __restrict__ lenv, unsigned short* __restrict__ asp_bf,
    float* __restrict__ fac,
    const float* __restrict__ w1, unsigned short* __restrict__ w1b,
    const float* __restrict__ w2, unsigned short* __restrict__ w2b) {
  int bx = blockIdx.x;
  if (bx >= 512) {
    int blk = bx - 512;
    const float* src = (blk < 256) ? w1 : w2;
    unsigned short* dst = (blk < 256) ? w1b : w2b;
    int i = ((blk & 255) * 256 + threadIdx.x) * 4;
    float4 v = *(const float4*)(src + i);
    ushort4 o; o.x = f2bf(v.x); o.y = f2bf(v.y); o.z = f2bf(v.z); o.w = f2bf(v.w);
    *(ushort4*)(dst + i) = o;
    return;
  }
  __shared__ float cs[512];
  int b = bx >> 6;
  int s0 = (bx & 63) * 16;
  int tid = threadIdx.x;
#pragma unroll
  for (int h = 0; h < 2; ++h) {
    int d = h * 256 + tid;
    float s = 0.f;
    const float* p = partial + (size_t)b * 32 * Dq + d;
#pragma unroll
    for (int t = 0; t < 32; ++t) s += p[t * Dq];
    cs[d] = s;
  }
  __syncthreads();
  int lane = tid & 63, wave = tid >> 6;
  int g = lane >> 4, lr = lane & 15;
  int row = s0 + wave * 4 + g;  // row within batch
  const float* a = aspect + ((size_t)b * Sq + row) * Dq + lr * 32;
  unsigned short* dst = asp_bf + ((size_t)b * Sq + row) * Dq + lr * 32;
  float sum = 0.f;
#pragma unroll
  for (int j = 0; j < 8; ++j) {
    float4 v = *(const float4*)(a + j * 4);
    ushort4 o; o.x = f2bf(v.x); o.y = f2bf(v.y); o.z = f2bf(v.z); o.w = f2bf(v.w);
    *(ushort4*)(dst + j * 4) = o;
    const float* c = cs + lr * 32 + j * 4;
    sum += v.x * c[0] + v.y * c[1] + v.z * c[2] + v.w * c[3];
  }
#pragma unroll
  for (int off = 1; off < 16; off <<= 1) sum += __shfl_xor(sum, off, 64);
  if (lr == 0) {
    float len = lenv[b];
    float scale = sqrtf(len);
    float f = 0.f;
    if (row < (int)len) f = 1.f / (scale * (sum / scale + 1e-4f));
    fac[b * Sq + row] = f;
  }
}

// ---- Gram GEMM, symmetric: only bn>=bm blocks work; bn>bm writes C and C^T ----
__global__ __launch_bounds__(256, 5) void gemm_gram(
    const unsigned short* __restrict__ Ag, int K, long strideA, long strideO,
    unsigned short* __restrict__ outBf) {
  int b = blockIdx.x, bm = blockIdx.y, bn = blockIdx.z;
  if (bn < bm) return;
  __shared__ unsigned short sA[2][64 * 64];
  __shared__ unsigned short sB[2][64 * 64];
  const unsigned short* Ab = Ag + (size_t)b * strideA + (size_t)bm * 64 * K;
  const unsigned short* Bb = Ag + (size_t)b * strideA + (size_t)bn * 64 * K;
  int tid = threadIdx.x;
  int lane = tid & 63, wave = tid >> 6;
  int wm = (wave >> 1) * 32, wn = (wave & 1) * 32;
  int lr = lane & 15, lq = lane >> 4;
  int x7 = lr & 7;
  int l3 = lane >> 3, l7 = lane & 7;

  int r0 = wave * 16;
  const unsigned short* gA = Ab + (size_t)(r0 + l3) * K + (l7 ^ l3) * 8;
  const unsigned short* gB = Bb + (size_t)(r0 + l3) * K + (l7 ^ l3) * 8;
  int dbase0 = (r0 * 8 + lane) * 8;
  int dbase1 = ((r0 + 8) * 8 + lane) * 8;

  f32x4 acc[2][2] = {};

  auto issue = [&](int buf, int k0) {
    load_lds16(gA + k0, &sA[buf][dbase0]);
    load_lds16(gA + (size_t)8 * K + k0, &sA[buf][dbase1]);
    load_lds16(gB + k0, &sB[buf][dbase0]);
    load_lds16(gB + (size_t)8 * K + k0, &sB[buf][dbase1]);
  };

  const int nk = K >> 6;
  issue(0, 0);
#pragma unroll
  for (int it = 0; it < nk; ++it) {
    int cur = it & 1;
    __syncthreads();
    if (it + 1 < nk) issue(cur ^ 1, (it + 1) << 6);
#pragma unroll
    for (int c = 0; c < 2; ++c) {
      int g = c * 4 + lq;
      bf16x8 a0 = *(const bf16x8*)&sA[cur][((wm + lr) * 8 + (g ^ x7)) * 8];
      bf16x8 a1 = *(const bf16x8*)&sA[cur][((wm + 16 + lr) * 8 + (g ^ x7)) * 8];
      bf16x8 b0 = *(const bf16x8*)&sB[cur][((wn + lr) * 8 + (g ^ x7)) * 8];
      bf16x8 b1 = *(const bf16x8*)&sB[cur][((wn + 16 + lr) * 8 + (g ^ x7)) * 8];
      acc[0][0] = __builtin_amdgcn_mfma_f32_16x16x32_bf16(a0, b0, acc[0][0], 0, 0, 0);
      acc[0][1] = __builtin_amdgcn_mfma_f32_16x16x32_bf16(a0, b1, acc[0][1], 0, 0, 0);
      acc[1][0] = __builtin_amdgcn_mfma_f32_16x16x32_bf16(a1, b0, acc[1][0], 0, 0, 0);
      acc[1][1] = __builtin_amdgcn_mfma_f32_16x16x32_bf16(a1, b1, acc[1][1], 0, 0, 0);
    }
  }

  unsigned short* Ob = outBf + (size_t)b * strideO;
#pragma unroll
  for (int mi = 0; mi < 2; ++mi)
#pragma unroll
    for (int ni = 0; ni < 2; ++ni)
#pragma unroll
      for (int i = 0; i < 4; ++i) {
        int r = bm * 64 + wm + mi * 16 + lq * 4 + i;
        int cc = bn * 64 + wn + ni * 16 + lr;
        unsigned short h = f2bf(acc[mi][ni][i]);
        Ob[(size_t)r * 512 + cc] = h;
        if (bn > bm) Ob[(size_t)cc * 512 + r] = h;
      }
}

// ---- MEGA: W + FFN1 + FFN2 + norm; 16-row stripes, 512 blocks (2/CU),
// 49 KB static LDS, single-buffered 32KB wbuf B-staging, XCD-pinned batch ----
#define LPA 520

__global__ __launch_bounds__(512, 4) void mega_ffn(
    const unsigned short* __restrict__ aspb, const unsigned short* __restrict__ G,
    const unsigned short* __restrict__ w1b, const unsigned short* __restrict__ w2b,
    const float* __restrict__ b1, const float* __restrict__ b2,
    const float* __restrict__ inp, const float* __restrict__ aspect,
    const float* __restrict__ fac, const float* __restrict__ lenv,
    float* __restrict__ out) {
  __shared__ unsigned short ldsA[16 * LPA];  // 16.6 KB
  __shared__ unsigned short wbuf[512 * 32];  // 32 KB
  __shared__ float ssqW[8 * 16];
  int tid = threadIdx.x;
  int lane = tid & 63, wave = tid >> 6;  // wave == ng in [0,8)
  int lr = lane & 15, lq = lane >> 4;
  int b = blockIdx.x & 7;                 // XCD pin: XCD k serves batch k
  int s0 = (blockIdx.x >> 3) * 16;        // stripe start within batch
  int c0 = wave * 64;

  bf16x8 af[16];
  f32x4 acc[4];
  f32x4 ffnv[4];

  auto stage = [&](int kc, const unsigned short* Bsrc) {
#pragma unroll
    for (int i = 0; i < 4; ++i) {
      int n = i * 128 + wave * 16 + (lane >> 2);
      load_lds16(Bsrc + (size_t)n * 512 + kc * 32 + (lane & 3) * 8,
                 wbuf + (size_t)(i * 512 + wave * 64 + lane) * 8);
    }
  };

  auto gemmPhase = [&](const unsigned short* Bsrc) {
#pragma unroll
    for (int t = 0; t < 4; ++t) acc[t] = (f32x4){0.f, 0.f, 0.f, 0.f};
#pragma unroll
    for (int kc = 0; kc < 16; ++kc) {
      stage(kc, Bsrc);
      __syncthreads();  // staged data visible
      bf16x8 bfr[4];
#pragma unroll
      for (int t = 0; t < 4; ++t)
        bfr[t] = *(const bf16x8*)&wbuf[(size_t)((c0 + t * 16 + lr) * 4 + lq) * 8];
#pragma unroll
      for (int t = 0; t < 4; ++t)
        acc[t] = __builtin_amdgcn_mfma_f32_16x16x32_bf16(af[kc], bfr[t], acc[t], 0, 0, 0);
      __syncthreads();  // reads done before next overwrite
    }
  };

  // ---- phase 0: ffn = fac * (asp @ G^T) + (inp+aspect)*mask ----
  const unsigned short* aspRow = aspb + ((size_t)b * Sq + s0 + lr) * Dq;
#pragma unroll
  for (int j = 0; j < 16; ++j)
    af[j] = *(const bf16x8*)(aspRow + j * 32 + lq * 8);
  gemmPhase(G + (size_t)b * 512 * 512);
  int len = (int)lenv[b];
  float facv[4];
#pragma unroll
  for (int i = 0; i < 4; ++i) facv[i] = fac[b * Sq + s0 + lq * 4 + i];
#pragma unroll
  for (int t = 0; t < 4; ++t) {
#pragma unroll
    for (int i = 0; i < 4; ++i) {
      int rl = s0 + lq * 4 + i;
      size_t idx = ((size_t)b * Sq + rl) * Dq + c0 + t * 16 + lr;
      float add = (rl < len) ? (inp[idx] + aspect[idx]) : 0.f;
      float v = acc[t][i] * facv[i] + add;
      ffnv[t][i] = v;
      ldsA[(lq * 4 + i) * LPA + c0 + t * 16 + lr] = f2bf(v);
    }
  }
  __syncthreads();

  // ---- phase 1: o1 = relu(ffn @ w1^T + b1) ----
#pragma unroll
  for (int j = 0; j < 16; ++j)
    af[j] = *(const bf16x8*)&ldsA[lr * LPA + j * 32 + lq * 8];
  __syncthreads();
  gemmPhase(w1b);
  float biasv[4];
#pragma unroll
  for (int t = 0; t < 4; ++t) biasv[t] = b1[c0 + t * 16 + lr];
#pragma unroll
  for (int t = 0; t < 4; ++t)
#pragma unroll
    for (int i = 0; i < 4; ++i)
      ldsA[(lq * 4 + i) * LPA + c0 + t * 16 + lr] =
          f2bf(fmaxf(acc[t][i] + biasv[t], 0.f));
  __syncthreads();

  // ---- phase 2: final = 2*ffn + relu(o1 @ w2^T + b2), then normalize ----
#pragma unroll
  for (int j = 0; j < 16; ++j)
    af[j] = *(const bf16x8*)&ldsA[lr * LPA + j * 32 + lq * 8];
  __syncthreads();
  gemmPhase(w2b);
#pragma unroll
  for (int t = 0; t < 4; ++t) biasv[t] = b2[c0 + t * 16 + lr];
  float ssq[4] = {0.f, 0.f, 0.f, 0.f};
#pragma unroll
  for (int t = 0; t < 4; ++t)
#pragma unroll
    for (int i = 0; i < 4; ++i) {
      float v = 2.f * ffnv[t][i] + fmaxf(acc[t][i] + biasv[t], 0.f);
      ffnv[t][i] = v;
      ssq[i] += v * v;
    }
#pragma unroll
  for (int off = 1; off < 16; off <<= 1)
#pragma unroll
    for (int i = 0; i < 4; ++i) ssq[i] += __shfl_xor(ssq[i], off, 64);
  if (lr == 0)
#pragma unroll
    for (int i = 0; i < 4; ++i) ssqW[wave * 16 + lq * 4 + i] = ssq[i];
  __syncthreads();
  float rn[4];
#pragma unroll
  for (int i = 0; i < 4; ++i) {
    float s = 0.f;
#pragma unroll
    for (int g = 0; g < 8; ++g) s += ssqW[g * 16 + lq * 4 + i];
    rn[i] = 1.f / sqrtf(s);
  }
#pragma unroll
  for (int t = 0; t < 4; ++t)
#pragma unroll
    for (int i = 0; i < 4; ++i) {
      size_t idx = ((size_t)b * Sq + s0 + lq * 4 + i) * Dq + c0 + t * 16 + lr;
      out[idx] = ffnv[t][i] * rn[i];
    }
}

extern "C" void kernel_launch(void* const* d_in, const int* in_sizes, int n_in,
                              void* d_out, int out_size, void* d_ws, size_t ws_size,
                              hipStream_t stream) {
  const float* inp = (const float*)d_in[0];
  const float* inp_len = (const float*)d_in[1];
  const float* aspect = (const float*)d_in[2];
  const float* w1 = (const float*)d_in[3];
  const float* b1 = (const float*)d_in[4];
  const float* w2 = (const float*)d_in[5];
  const float* b2 = (const float*)d_in[6];
  float* out = (float*)d_out;

  char* W = (char*)d_ws;
  const size_t MB = 1ull << 20;
  unsigned short* asp_bf = (unsigned short*)(W + 0);        // 8 MB  [B][S][D]
  unsigned short* inpT   = (unsigned short*)(W + 8 * MB);   // 8 MB  [B][D][S]
  unsigned short* Gm     = (unsigned short*)(W + 16 * MB);  // 4 MB  [B][D][D]
  unsigned short* w1bf   = (unsigned short*)(W + 20 * MB);  // 512 KB
  unsigned short* w2bf   = (unsigned short*)(W + 20 * MB + 512 * 1024);
  float*          partial= (float*)(W + 21 * MB);           // 512 KB [B][32][D]
  float*          fac    = (float*)(W + 22 * MB);           // 32 KB

  // 1) inp pass: transpose + colsum partials
  prep_inp<<<dim3(8, 32, 16), dim3(32, 8), 0, stream>>>(inp, inpT, partial);

  // 2) aspect pass (exact fp32 fac) + w1/w2 conversion
  prep_asp<<<1024, 256, 0, stream>>>(aspect, partial, inp_len, asp_bf, fac,
                                     w1, w1bf, w2, w2bf);

  // 3) Gram: G[b] = inpT[b] @ inpT[b]^T (symmetric; upper-triangle blocks only)
  gemm_gram<<<dim3(8, 8, 8), 256, 0, stream>>>(
      inpT, 1024, (long)Dq * Sq, (long)Dq * Dq, Gm);

  // 4) MEGA: W + FFN1 + FFN2 + norm (16 rows/block, 512 blocks, 2/CU)
  mega_ffn<<<512, 512, 0, stream>>>(
      asp_bf, Gm, w1bf, w2bf, b1, b2, inp, aspect, fac, inp_len, out);
}

// Round 12
// 160.867 us; speedup vs baseline: 1.0926x; 1.0926x over previous
//
#include <hip/hip_runtime.h>

#define Bq 8
#define Sq 1024
#define Dq 512

typedef __attribute__((ext_vector_type(8))) short bf16x8;
typedef __attribute__((ext_vector_type(4))) float f32x4;

__device__ __forceinline__ unsigned short f2bf(float f) {
  unsigned int u = __float_as_uint(f);
  return (unsigned short)((u + 0x7fffu + ((u >> 16) & 1u)) >> 16);
}

__device__ __forceinline__ void load_lds16(const unsigned short* g, unsigned short* l) {
  __builtin_amdgcn_global_load_lds(
      (const __attribute__((address_space(1))) unsigned int*)g,
      (__attribute__((address_space(3))) unsigned int*)l, 16, 0, 0);
}

// ---- prep_inp: transpose to inpT (bf16) + race-free colsum partials ----
__global__ void prep_inp(const float* __restrict__ inp, unsigned short* __restrict__ inpT,
                         float* __restrict__ partial) {
  __shared__ unsigned short tile[32][33];
  __shared__ float csum[8][33];
  int b = blockIdx.x;
  int t0 = blockIdx.y * 32, d0 = blockIdx.z * 32;
  int tx = threadIdx.x, ty = threadIdx.y;
  const float* src = inp + ((size_t)b * Sq + t0) * Dq + d0;
  float part = 0.f;
#pragma unroll
  for (int i = 0; i < 4; ++i) {
    float v = src[(size_t)(ty + i * 8) * Dq + tx];
    tile[ty + i * 8][tx] = f2bf(v);
    part += v;
  }
  csum[ty][tx] = part;
  __syncthreads();
  unsigned short* dst = inpT + (size_t)b * Dq * Sq;
#pragma unroll
  for (int i = 0; i < 4; ++i)
    dst[(size_t)(d0 + ty + i * 8) * Sq + t0 + tx] = tile[tx][ty + i * 8];
  if (ty == 0) {
    float s = 0.f;
#pragma unroll
    for (int i = 0; i < 8; ++i) s += csum[i][tx];
    partial[((size_t)b * 32 + blockIdx.y) * Dq + d0 + tx] = s;
  }
}

// ---- prep_asp: 16 rows/block; colsum reduced once per block into LDS;
// exact fp32 fac; asp bf16 cast; blocks >=512 convert w1/w2 ----
__global__ __launch_bounds__(256) void prep_asp(
    const float* __restrict__ aspect, const float* __restrict__ partial,
    const float* __restrict__ lenv, unsigned short* __restrict__ asp_bf,
    float* __restrict__ fac,
    const float* __restrict__ w1, unsigned short* __restrict__ w1b,
    const float* __restrict__ w2, unsigned short* __restrict__ w2b) {
  int bx = blockIdx.x;
  if (bx >= 512) {
    int blk = bx - 512;
    const float* src = (blk < 256) ? w1 : w2;
    unsigned short* dst = (blk < 256) ? w1b : w2b;
    int i = ((blk & 255) * 256 + threadIdx.x) * 4;
    float4 v = *(const float4*)(src + i);
    ushort4 o; o.x = f2bf(v.x); o.y = f2bf(v.y); o.z = f2bf(v.z); o.w = f2bf(v.w);
    *(ushort4*)(dst + i) = o;
    return;
  }
  __shared__ float cs[512];
  int b = bx >> 6;
  int s0 = (bx & 63) * 16;
  int tid = threadIdx.x;
#pragma unroll
  for (int h = 0; h < 2; ++h) {
    int d = h * 256 + tid;
    float s = 0.f;
    const float* p = partial + (size_t)b * 32 * Dq + d;
#pragma unroll
    for (int t = 0; t < 32; ++t) s += p[t * Dq];
    cs[d] = s;
  }
  __syncthreads();
  int lane = tid & 63, wave = tid >> 6;
  int g = lane >> 4, lr = lane & 15;
  int row = s0 + wave * 4 + g;
  const float* a = aspect + ((size_t)b * Sq + row) * Dq + lr * 32;
  unsigned short* dst = asp_bf + ((size_t)b * Sq + row) * Dq + lr * 32;
  float sum = 0.f;
#pragma unroll
  for (int j = 0; j < 8; ++j) {
    float4 v = *(const float4*)(a + j * 4);
    ushort4 o; o.x = f2bf(v.x); o.y = f2bf(v.y); o.z = f2bf(v.z); o.w = f2bf(v.w);
    *(ushort4*)(dst + j * 4) = o;
    const float* c = cs + lr * 32 + j * 4;
    sum += v.x * c[0] + v.y * c[1] + v.z * c[2] + v.w * c[3];
  }
#pragma unroll
  for (int off = 1; off < 16; off <<= 1) sum += __shfl_xor(sum, off, 64);
  if (lr == 0) {
    float len = lenv[b];
    float scale = sqrtf(len);
    float f = 0.f;
    if (row < (int)len) f = 1.f / (scale * (sum / scale + 1e-4f));
    fac[b * Sq + row] = f;
  }
}

// ---- Gram GEMM, symmetric: bn<bm blocks exit; bn>bm writes C and C^T ----
__global__ __launch_bounds__(256, 5) void gemm_gram(
    const unsigned short* __restrict__ Ag, int K, long strideA, long strideO,
    unsigned short* __restrict__ outBf) {
  int b = blockIdx.x, bm = blockIdx.y, bn = blockIdx.z;
  if (bn < bm) return;
  __shared__ unsigned short sA[2][64 * 64];
  __shared__ unsigned short sB[2][64 * 64];
  const unsigned short* Ab = Ag + (size_t)b * strideA + (size_t)bm * 64 * K;
  const unsigned short* Bb = Ag + (size_t)b * strideA + (size_t)bn * 64 * K;
  int tid = threadIdx.x;
  int lane = tid & 63, wave = tid >> 6;
  int wm = (wave >> 1) * 32, wn = (wave & 1) * 32;
  int lr = lane & 15, lq = lane >> 4;
  int x7 = lr & 7;
  int l3 = lane >> 3, l7 = lane & 7;

  int r0 = wave * 16;
  const unsigned short* gA = Ab + (size_t)(r0 + l3) * K + (l7 ^ l3) * 8;
  const unsigned short* gB = Bb + (size_t)(r0 + l3) * K + (l7 ^ l3) * 8;
  int dbase0 = (r0 * 8 + lane) * 8;
  int dbase1 = ((r0 + 8) * 8 + lane) * 8;

  f32x4 acc[2][2] = {};

  auto issue = [&](int buf, int k0) {
    load_lds16(gA + k0, &sA[buf][dbase0]);
    load_lds16(gA + (size_t)8 * K + k0, &sA[buf][dbase1]);
    load_lds16(gB + k0, &sB[buf][dbase0]);
    load_lds16(gB + (size_t)8 * K + k0, &sB[buf][dbase1]);
  };

  const int nk = K >> 6;
  issue(0, 0);
#pragma unroll
  for (int it = 0; it < nk; ++it) {
    int cur = it & 1;
    __syncthreads();
    if (it + 1 < nk) issue(cur ^ 1, (it + 1) << 6);
#pragma unroll
    for (int c = 0; c < 2; ++c) {
      int g = c * 4 + lq;
      bf16x8 a0 = *(const bf16x8*)&sA[cur][((wm + lr) * 8 + (g ^ x7)) * 8];
      bf16x8 a1 = *(const bf16x8*)&sA[cur][((wm + 16 + lr) * 8 + (g ^ x7)) * 8];
      bf16x8 b0 = *(const bf16x8*)&sB[cur][((wn + lr) * 8 + (g ^ x7)) * 8];
      bf16x8 b1 = *(const bf16x8*)&sB[cur][((wn + 16 + lr) * 8 + (g ^ x7)) * 8];
      acc[0][0] = __builtin_amdgcn_mfma_f32_16x16x32_bf16(a0, b0, acc[0][0], 0, 0, 0);
      acc[0][1] = __builtin_amdgcn_mfma_f32_16x16x32_bf16(a0, b1, acc[0][1], 0, 0, 0);
      acc[1][0] = __builtin_amdgcn_mfma_f32_16x16x32_bf16(a1, b0, acc[1][0], 0, 0, 0);
      acc[1][1] = __builtin_amdgcn_mfma_f32_16x16x32_bf16(a1, b1, acc[1][1], 0, 0, 0);
    }
  }

  unsigned short* Ob = outBf + (size_t)b * strideO;
#pragma unroll
  for (int mi = 0; mi < 2; ++mi)
#pragma unroll
    for (int ni = 0; ni < 2; ++ni)
#pragma unroll
      for (int i = 0; i < 4; ++i) {
        int r = bm * 64 + wm + mi * 16 + lq * 4 + i;
        int cc = bn * 64 + wn + ni * 16 + lr;
        unsigned short h = f2bf(acc[mi][ni][i]);
        Ob[(size_t)r * 512 + cc] = h;
        if (bn > bm) Ob[(size_t)cc * 512 + r] = h;
      }
}

// ---- 64x64 tile, BK=64, dbuf, 5 blocks/CU bf16 MFMA GEMM: C = A*B^T ----
// (R8's proven kernel) EPI 2: W epilogue; EPI 3: relu+b1 -> bf16;
// EPI 4: 2*resid + relu(+b2) -> fp32.
struct EpiArgs {
  const float* fac;
  const float* inp;
  const float* aspect;
  const float* lenv;
  const float* bias;
  const float* resid;
  float* outF;
  unsigned short* outBf;
};

template <int EPI, int MODE, int K>
__global__ __launch_bounds__(256, 5) void gemm_bf16(
    const unsigned short* __restrict__ Ag, const unsigned short* __restrict__ Bg,
    int M, int N, long strideA, long strideB, long strideOF, long strideOBf,
    EpiArgs e) {
  __shared__ unsigned short sA[2][64 * 64];
  __shared__ unsigned short sB[2][64 * 64];
  int b, bm, bn;
  if (MODE == 0) { b = blockIdx.x; bm = blockIdx.y; bn = blockIdx.z; }
  else           { b = 0; bm = blockIdx.x; bn = blockIdx.y; }
  const unsigned short* Ab = Ag + (size_t)b * strideA + (size_t)bm * 64 * K;
  const unsigned short* Bb = Bg + (size_t)b * strideB + (size_t)bn * 64 * K;
  int tid = threadIdx.x;
  int lane = tid & 63, wave = tid >> 6;
  int wm = (wave >> 1) * 32, wn = (wave & 1) * 32;
  int lr = lane & 15, lq = lane >> 4;
  int x7 = lr & 7;
  int l3 = lane >> 3, l7 = lane & 7;

  int r0 = wave * 16;
  const unsigned short* gA = Ab + (size_t)(r0 + l3) * K + (l7 ^ l3) * 8;
  const unsigned short* gB = Bb + (size_t)(r0 + l3) * K + (l7 ^ l3) * 8;
  int dbase0 = (r0 * 8 + lane) * 8;
  int dbase1 = ((r0 + 8) * 8 + lane) * 8;

  f32x4 acc[2][2] = {};

  auto issue = [&](int buf, int k0) {
    load_lds16(gA + k0, &sA[buf][dbase0]);
    load_lds16(gA + (size_t)8 * K + k0, &sA[buf][dbase1]);
    load_lds16(gB + k0, &sB[buf][dbase0]);
    load_lds16(gB + (size_t)8 * K + k0, &sB[buf][dbase1]);
  };

  const int nk = K >> 6;
  issue(0, 0);
#pragma unroll
  for (int it = 0; it < nk; ++it) {
    int cur = it & 1;
    __syncthreads();
    if (it + 1 < nk) issue(cur ^ 1, (it + 1) << 6);
#pragma unroll
    for (int c = 0; c < 2; ++c) {
      int g = c * 4 + lq;
      bf16x8 a0 = *(const bf16x8*)&sA[cur][((wm + lr) * 8 + (g ^ x7)) * 8];
      bf16x8 a1 = *(const bf16x8*)&sA[cur][((wm + 16 + lr) * 8 + (g ^ x7)) * 8];
      bf16x8 b0 = *(const bf16x8*)&sB[cur][((wn + lr) * 8 + (g ^ x7)) * 8];
      bf16x8 b1 = *(const bf16x8*)&sB[cur][((wn + 16 + lr) * 8 + (g ^ x7)) * 8];
      acc[0][0] = __builtin_amdgcn_mfma_f32_16x16x32_bf16(a0, b0, acc[0][0], 0, 0, 0);
      acc[0][1] = __builtin_amdgcn_mfma_f32_16x16x32_bf16(a0, b1, acc[0][1], 0, 0, 0);
      acc[1][0] = __builtin_amdgcn_mfma_f32_16x16x32_bf16(a1, b0, acc[1][0], 0, 0, 0);
      acc[1][1] = __builtin_amdgcn_mfma_f32_16x16x32_bf16(a1, b1, acc[1][1], 0, 0, 0);
    }
  }

#pragma unroll
  for (int mi = 0; mi < 2; ++mi) {
#pragma unroll
    for (int ni = 0; ni < 2; ++ni) {
#pragma unroll
      for (int i = 0; i < 4; ++i) {
        int r = bm * 64 + wm + mi * 16 + lq * 4 + i;
        int cc = bn * 64 + wn + ni * 16 + lr;
        float v = acc[mi][ni][i];
        if (EPI == 2) {
          float f = e.fac[(size_t)b * M + r];
          int len = (int)e.lenv[b];
          size_t idx = (size_t)b * ((size_t)Sq * Dq) + (size_t)r * Dq + cc;
          float add = (r < len) ? (e.inp[idx] + e.aspect[idx]) : 0.f;
          float o = v * f + add;
          e.outF[(size_t)b * strideOF + (size_t)r * N + cc] = o;
          e.outBf[(size_t)b * strideOBf + (size_t)r * N + cc] = f2bf(o);
        } else if (EPI == 3) {
          float o = fmaxf(v + e.bias[cc], 0.f);
          e.outBf[(size_t)r * N + cc] = f2bf(o);
        } else {
          float o = fmaxf(v + e.bias[cc], 0.f);
          size_t idx = (size_t)r * N + cc;
          e.outF[idx] = 2.f * e.resid[idx] + o;
        }
      }
    }
  }
}

// ---- out[row] = final[row] / ||final[row]|| ----
__global__ void norm_kernel(const float* __restrict__ fin, float* __restrict__ out) {
  int row = blockIdx.x * 4 + (threadIdx.x >> 6);
  int lane = threadIdx.x & 63;
  const float* p = fin + (size_t)row * Dq;
  float4 v0 = *(const float4*)(p + lane * 8);
  float4 v1 = *(const float4*)(p + lane * 8 + 4);
  float ss = v0.x * v0.x + v0.y * v0.y + v0.z * v0.z + v0.w * v0.w +
             v1.x * v1.x + v1.y * v1.y + v1.z * v1.z + v1.w * v1.w;
#pragma unroll
  for (int o = 32; o; o >>= 1) ss += __shfl_xor(ss, o, 64);
  float rn = 1.f / sqrtf(ss);
  float* q = out + (size_t)row * Dq;
  v0.x *= rn; v0.y *= rn; v0.z *= rn; v0.w *= rn;
  v1.x *= rn; v1.y *= rn; v1.z *= rn; v1.w *= rn;
  *(float4*)(q + lane * 8) = v0;
  *(float4*)(q + lane * 8 + 4) = v1;
}

extern "C" void kernel_launch(void* const* d_in, const int* in_sizes, int n_in,
                              void* d_out, int out_size, void* d_ws, size_t ws_size,
                              hipStream_t stream) {
  const float* inp = (const float*)d_in[0];
  const float* inp_len = (const float*)d_in[1];
  const float* aspect = (const float*)d_in[2];
  const float* w1 = (const float*)d_in[3];
  const float* b1 = (const float*)d_in[4];
  const float* w2 = (const float*)d_in[5];
  const float* b2 = (const float*)d_in[6];
  float* out = (float*)d_out;

  char* W = (char*)d_ws;
  const size_t MB = 1ull << 20;
  unsigned short* asp_bf = (unsigned short*)(W + 0);        // 8 MB  [B][S][D]
  unsigned short* inpT   = (unsigned short*)(W + 8 * MB);   // 8 MB  [B][D][S]
  unsigned short* Gm     = (unsigned short*)(W + 16 * MB);  // 4 MB  [B][D][D]
  unsigned short* w1bf   = (unsigned short*)(W + 20 * MB);  // 512 KB
  unsigned short* w2bf   = (unsigned short*)(W + 20 * MB + 512 * 1024);
  float*          partial= (float*)(W + 21 * MB);           // 512 KB [B][32][D]
  float*          fac    = (float*)(W + 22 * MB);           // 32 KB
  float*          ffnF   = (float*)(W + 24 * MB);           // 16 MB [B*S][D] fp32
  unsigned short* ffnBf  = (unsigned short*)(W + 40 * MB);  // 8 MB
  unsigned short* o1b    = (unsigned short*)(W + 48 * MB);  // 8 MB
  float*          finalF = (float*)(W + 56 * MB);           // 16 MB

  // 1) inp pass: transpose + colsum partials
  prep_inp<<<dim3(8, 32, 16), dim3(32, 8), 0, stream>>>(inp, inpT, partial);

  // 2) aspect pass (exact fp32 fac) + w1/w2 conversion
  prep_asp<<<1024, 256, 0, stream>>>(aspect, partial, inp_len, asp_bf, fac,
                                     w1, w1bf, w2, w2bf);

  // 3) Gram: G[b] = inpT[b] @ inpT[b]^T (symmetric, upper-triangle work)
  gemm_gram<<<dim3(8, 8, 8), 256, 0, stream>>>(
      inpT, 1024, (long)Dq * Sq, (long)Dq * Dq, Gm);

  // 4) W: ffn_inp = fac ⊙ (asp @ G^T) + (inp+aspect)*mask   M=1024 N=512 K=512
  {
    EpiArgs e{};
    e.fac = fac; e.inp = inp; e.aspect = aspect; e.lenv = inp_len;
    e.outF = ffnF; e.outBf = ffnBf;
    gemm_bf16<2, 0, 512><<<dim3(8, 16, 8), 256, 0, stream>>>(
        asp_bf, Gm, 1024, 512,
        (long)Sq * Dq, (long)Dq * Dq, (long)Sq * Dq, (long)Sq * Dq, e);
  }
  // 5) FFN1: o1 = relu(ffn @ w1^T + b1)   M=8192 N=512 K=512
  {
    EpiArgs e{};
    e.bias = b1; e.outBf = o1b;
    gemm_bf16<3, 1, 512><<<dim3(128, 8), 256, 0, stream>>>(
        ffnBf, w1bf, 8192, 512, 0, 0, 0, 0, e);
  }
  // 6) FFN2: final = 2*ffn + relu(o1 @ w2^T + b2)   M=8192 N=512 K=512
  {
    EpiArgs e{};
    e.bias = b2; e.resid = ffnF; e.outF = finalF;
    gemm_bf16<4, 1, 512><<<dim3(128, 8), 256, 0, stream>>>(
        o1b, w2bf, 8192, 512, 0, 0, 0, 0, e);
  }
  // 7) normalize rows
  norm_kernel<<<2048, 256, 0, stream>>>(finalF, out);
}

// Round 13
// 153.283 us; speedup vs baseline: 1.1467x; 1.0495x over previous
//
#include <hip/hip_runtime.h>

#define Bq 8
#define Sq 1024
#define Dq 512

typedef __attribute__((ext_vector_type(8))) short bf16x8;
typedef __attribute__((ext_vector_type(4))) float f32x4;

__device__ __forceinline__ unsigned short f2bf(float f) {
  unsigned int u = __float_as_uint(f);
  return (unsigned short)((u + 0x7fffu + ((u >> 16) & 1u)) >> 16);
}

__device__ __forceinline__ void load_lds16(const unsigned short* g, unsigned short* l) {
  __builtin_amdgcn_global_load_lds(
      (const __attribute__((address_space(1))) unsigned int*)g,
      (__attribute__((address_space(3))) unsigned int*)l, 16, 0, 0);
}

// ================= dispatch 1: prep_all =================
// f0 (idx<4096): inp transpose->inpT bf16 + race-free colsum partials
// f1 (4096..4608): aspect fp32->bf16 cast
// f2 (4608..5120): w1/w2 fp32->bf16 cast
__global__ __launch_bounds__(256) void prep_all(
    const float* __restrict__ inp, const float* __restrict__ aspect,
    const float* __restrict__ w1, const float* __restrict__ w2,
    unsigned short* __restrict__ inpT, float* __restrict__ partial,
    unsigned short* __restrict__ asp_bf,
    unsigned short* __restrict__ w1b, unsigned short* __restrict__ w2b) {
  __shared__ unsigned short tile[32][33];
  __shared__ float csum[8][33];
  int idx = blockIdx.x;
  int tid = threadIdx.x;
  if (idx < 4096) {
    int b = idx & 7;
    int tt = (idx >> 3) & 31;
    int t0 = tt * 32, d0 = (idx >> 8) * 32;
    int tx = tid & 31, ty = tid >> 5;
    const float* src = inp + ((size_t)b * Sq + t0) * Dq + d0;
    float part = 0.f;
#pragma unroll
    for (int i = 0; i < 4; ++i) {
      float v = src[(size_t)(ty + i * 8) * Dq + tx];
      tile[ty + i * 8][tx] = f2bf(v);
      part += v;
    }
    csum[ty][tx] = part;
    __syncthreads();
    unsigned short* dst = inpT + (size_t)b * Dq * Sq;
#pragma unroll
    for (int i = 0; i < 4; ++i)
      dst[(size_t)(d0 + ty + i * 8) * Sq + t0 + tx] = tile[tx][ty + i * 8];
    if (ty == 0) {
      float s = 0.f;
#pragma unroll
      for (int i = 0; i < 8; ++i) s += csum[i][tx];
      partial[((size_t)b * 32 + tt) * Dq + d0 + tx] = s;
    }
  } else if (idx < 4608) {
    int blk = idx - 4096;
    const float* s = aspect + (size_t)blk * 8192 + tid * 4;
    unsigned short* d = asp_bf + (size_t)blk * 8192 + tid * 4;
#pragma unroll
    for (int j = 0; j < 8; ++j) {
      float4 v = *(const float4*)(s + j * 1024);
      ushort4 o; o.x = f2bf(v.x); o.y = f2bf(v.y); o.z = f2bf(v.z); o.w = f2bf(v.w);
      *(ushort4*)(d + j * 1024) = o;
    }
  } else {
    int blk = idx - 4608;
    const float* src = (blk < 256) ? w1 : w2;
    unsigned short* dst = (blk < 256) ? w1b : w2b;
    int i = ((blk & 255) * 256 + tid) * 4;
    float4 v = *(const float4*)(src + i);
    ushort4 o; o.x = f2bf(v.x); o.y = f2bf(v.y); o.z = f2bf(v.z); o.w = f2bf(v.w);
    *(ushort4*)(dst + i) = o;
  }
}

// ================= dispatch 2: gram_fac =================
// blocks <1024: Gram 32x64 tiles (full matrix, balanced, XCD-pinned b=idx&7)
// blocks >=1024: fac (R12's measured-correct structure, 16 rows/block)
__global__ __launch_bounds__(256, 5) void gram_fac(
    const unsigned short* __restrict__ inpT, const float* __restrict__ partial,
    const float* __restrict__ aspect, const float* __restrict__ lenv,
    unsigned short* __restrict__ Gm, float* __restrict__ fac) {
  __shared__ unsigned short sA[2][32 * 64];  // 2 x 4 KB
  __shared__ unsigned short sB[2][64 * 64];  // 2 x 8 KB
  int idx = blockIdx.x;
  int tid = threadIdx.x;
  int lane = tid & 63, wave = tid >> 6;

  if (idx >= 1024) {
    // ---- fac family ----
    float* cs = (float*)sA;  // 512 floats, fits in sA
    int fblk = idx - 1024;
    int b = fblk >> 6;
    int s0 = (fblk & 63) * 16;
#pragma unroll
    for (int h = 0; h < 2; ++h) {
      int d = h * 256 + tid;
      float s = 0.f;
      const float* p = partial + (size_t)b * 32 * Dq + d;
#pragma unroll
      for (int t = 0; t < 32; ++t) s += p[t * Dq];
      cs[d] = s;
    }
    __syncthreads();
    int g = lane >> 4, lr = lane & 15;
    int row = s0 + wave * 4 + g;
    const float* a = aspect + ((size_t)b * Sq + row) * Dq + lr * 32;
    float sum = 0.f;
#pragma unroll
    for (int j = 0; j < 8; ++j) {
      float4 v = *(const float4*)(a + j * 4);
      const float* c = cs + lr * 32 + j * 4;
      sum += v.x * c[0] + v.y * c[1] + v.z * c[2] + v.w * c[3];
    }
#pragma unroll
    for (int off = 1; off < 16; off <<= 1) sum += __shfl_xor(sum, off, 64);
    if (lr == 0) {
      float len = lenv[b];
      float scale = sqrtf(len);
      float f = 0.f;
      if (row < (int)len) f = 1.f / (scale * (sum / scale + 1e-4f));
      fac[b * Sq + row] = f;
    }
    return;
  }

  // ---- gram family: C[32x64] = A(32 rows) * B(64 rows)^T over K=1024 ----
  const int K = 1024;
  int b = idx & 7;
  int tile = idx >> 3;
  int bm = tile & 15, bn = tile >> 4;
  const unsigned short* Ab = inpT + (size_t)b * Dq * Sq + (size_t)bm * 32 * K;
  const unsigned short* Bb = inpT + (size_t)b * Dq * Sq + (size_t)bn * 64 * K;
  int lr = lane & 15, lq = lane >> 4;
  int x7 = lr & 7;
  int l3 = lane >> 3, l7 = lane & 7;

  const unsigned short* gA = Ab + (size_t)(wave * 8 + l3) * K + (l7 ^ l3) * 8;
  const unsigned short* gB = Bb + (size_t)(wave * 16 + l3) * K + (l7 ^ l3) * 8;
  int dbaseA = (wave * 64 + lane) * 8;
  int dbaseB0 = (wave * 128 + lane) * 8;
  int dbaseB1 = (wave * 128 + 64 + lane) * 8;

  f32x4 acc[2] = {};

  auto issue = [&](int buf, int k0) {
    load_lds16(gA + k0, &sA[buf][dbaseA]);
    load_lds16(gB + k0, &sB[buf][dbaseB0]);
    load_lds16(gB + (size_t)8 * K + k0, &sB[buf][dbaseB1]);
  };

  int wm = (wave & 1) * 16, wn = (wave >> 1) * 32;
  issue(0, 0);
#pragma unroll
  for (int it = 0; it < 16; ++it) {
    int cur = it & 1;
    __syncthreads();
    if (it + 1 < 16) issue(cur ^ 1, (it + 1) << 6);
#pragma unroll
    for (int c = 0; c < 2; ++c) {
      int g = c * 4 + lq;
      bf16x8 a0 = *(const bf16x8*)&sA[cur][((wm + lr) * 8 + (g ^ x7)) * 8];
      bf16x8 b0 = *(const bf16x8*)&sB[cur][((wn + lr) * 8 + (g ^ x7)) * 8];
      bf16x8 b1 = *(const bf16x8*)&sB[cur][((wn + 16 + lr) * 8 + (g ^ x7)) * 8];
      acc[0] = __builtin_amdgcn_mfma_f32_16x16x32_bf16(a0, b0, acc[0], 0, 0, 0);
      acc[1] = __builtin_amdgcn_mfma_f32_16x16x32_bf16(a0, b1, acc[1], 0, 0, 0);
    }
  }

  unsigned short* Ob = Gm + (size_t)b * 512 * 512;
#pragma unroll
  for (int ni = 0; ni < 2; ++ni)
#pragma unroll
    for (int i = 0; i < 4; ++i) {
      int r = bm * 32 + wm + lq * 4 + i;
      int cc = bn * 64 + wn + ni * 16 + lr;
      Ob[(size_t)r * 512 + cc] = f2bf(acc[ni][i]);
    }
}

// ================= dispatch 3: mega (R10 verbatim, measured 52 us) =================
#define LP 520
#define MEGA_SMEM (32 * LP * 2 + 2 * 32768 + 512)

__global__ __launch_bounds__(512, 2) void mega_ffn(
    const unsigned short* __restrict__ aspb, const unsigned short* __restrict__ G,
    const unsigned short* __restrict__ w1b, const unsigned short* __restrict__ w2b,
    const float* __restrict__ b1, const float* __restrict__ b2,
    const float* __restrict__ inp, const float* __restrict__ aspect,
    const float* __restrict__ fac, const float* __restrict__ lenv,
    float* __restrict__ out) {
  extern __shared__ char smem[];
  unsigned short* ldsA = (unsigned short*)smem;
  unsigned short* wbuf = (unsigned short*)(smem + 32 * LP * 2);
  float* ssqW = (float*)(smem + 32 * LP * 2 + 2 * 32768);
  int tid = threadIdx.x;
  int lane = tid & 63, wave = tid >> 6;
  int mg = wave >> 2, ng = wave & 3;
  int lr = lane & 15, lq = lane >> 4;
  int r0 = blockIdx.x * 32;
  int b = r0 >> 10;
  int c0 = ng * 128;
  int arow = r0 + mg * 16 + lr;

  bf16x8 af[16];
  f32x4 acc[8];
  f32x4 ffnv[8];

  auto stage = [&](int buf, int kc, const unsigned short* Bsrc) {
#pragma unroll
    for (int i = 0; i < 4; ++i) {
      int n = i * 128 + wave * 16 + (lane >> 2);
      load_lds16(Bsrc + (size_t)n * 512 + kc * 32 + (lane & 3) * 8,
                 wbuf + buf * 16384 + (size_t)(i * 512 + wave * 64 + lane) * 8);
    }
  };

  auto gemmPhase = [&](const unsigned short* Bsrc) {
#pragma unroll
    for (int t = 0; t < 8; ++t) acc[t] = (f32x4){0.f, 0.f, 0.f, 0.f};
    stage(0, 0, Bsrc);
#pragma unroll
    for (int kc = 0; kc < 16; ++kc) {
      int cur = kc & 1;
      __syncthreads();
      if (kc < 15) stage(cur ^ 1, kc + 1, Bsrc);
      bf16x8 bfr[8];
#pragma unroll
      for (int t = 0; t < 8; ++t)
        bfr[t] = *(const bf16x8*)&wbuf[cur * 16384 + (size_t)((c0 + t * 16 + lr) * 4 + lq) * 8];
#pragma unroll
      for (int t = 0; t < 8; ++t)
        acc[t] = __builtin_amdgcn_mfma_f32_16x16x32_bf16(af[kc], bfr[t], acc[t], 0, 0, 0);
    }
  };

  // phase 0
#pragma unroll
  for (int j = 0; j < 16; ++j)
    af[j] = *(const bf16x8*)(aspb + (size_t)arow * 512 + j * 32 + lq * 8);
  gemmPhase(G + (size_t)b * 512 * 512);
  int len = (int)lenv[b];
  float facv[4];
#pragma unroll
  for (int i = 0; i < 4; ++i) facv[i] = fac[r0 + mg * 16 + lq * 4 + i];
#pragma unroll
  for (int t = 0; t < 8; ++t) {
#pragma unroll
    for (int i = 0; i < 4; ++i) {
      int r = r0 + mg * 16 + lq * 4 + i;
      size_t idx = (size_t)r * 512 + c0 + t * 16 + lr;
      float add = ((r & 1023) < len) ? (inp[idx] + aspect[idx]) : 0.f;
      float v = acc[t][i] * facv[i] + add;
      ffnv[t][i] = v;
      ldsA[(mg * 16 + lq * 4 + i) * LP + c0 + t * 16 + lr] = f2bf(v);
    }
  }
  __syncthreads();

  // phase 1
#pragma unroll
  for (int j = 0; j < 16; ++j)
    af[j] = *(const bf16x8*)&ldsA[(mg * 16 + lr) * LP + j * 32 + lq * 8];
  __syncthreads();
  gemmPhase(w1b);
  float biasv[8];
#pragma unroll
  for (int t = 0; t < 8; ++t) biasv[t] = b1[c0 + t * 16 + lr];
#pragma unroll
  for (int t = 0; t < 8; ++t)
#pragma unroll
    for (int i = 0; i < 4; ++i)
      ldsA[(mg * 16 + lq * 4 + i) * LP + c0 + t * 16 + lr] =
          f2bf(fmaxf(acc[t][i] + biasv[t], 0.f));
  __syncthreads();

  // phase 2 + norm
#pragma unroll
  for (int j = 0; j < 16; ++j)
    af[j] = *(const bf16x8*)&ldsA[(mg * 16 + lr) * LP + j * 32 + lq * 8];
  __syncthreads();
  gemmPhase(w2b);
#pragma unroll
  for (int t = 0; t < 8; ++t) biasv[t] = b2[c0 + t * 16 + lr];
  float ssq[4] = {0.f, 0.f, 0.f, 0.f};
#pragma unroll
  for (int t = 0; t < 8; ++t)
#pragma unroll
    for (int i = 0; i < 4; ++i) {
      float v = 2.f * ffnv[t][i] + fmaxf(acc[t][i] + biasv[t], 0.f);
      ffnv[t][i] = v;
      ssq[i] += v * v;
    }
#pragma unroll
  for (int off = 1; off < 16; off <<= 1)
#pragma unroll
    for (int i = 0; i < 4; ++i) ssq[i] += __shfl_xor(ssq[i], off, 64);
  if (lr == 0)
#pragma unroll
    for (int i = 0; i < 4; ++i) ssqW[(mg * 4 + ng) * 16 + lq * 4 + i] = ssq[i];
  __syncthreads();
  float rn[4];
#pragma unroll
  for (int i = 0; i < 4; ++i) {
    float s = ssqW[(mg * 4 + 0) * 16 + lq * 4 + i] + ssqW[(mg * 4 + 1) * 16 + lq * 4 + i] +
              ssqW[(mg * 4 + 2) * 16 + lq * 4 + i] + ssqW[(mg * 4 + 3) * 16 + lq * 4 + i];
    rn[i] = 1.f / sqrtf(s);
  }
#pragma unroll
  for (int t = 0; t < 8; ++t)
#pragma unroll
    for (int i = 0; i < 4; ++i) {
      int r = r0 + mg * 16 + lq * 4 + i;
      out[(size_t)r * 512 + c0 + t * 16 + lr] = ffnv[t][i] * rn[i];
    }
}

extern "C" void kernel_launch(void* const* d_in, const int* in_sizes, int n_in,
                              void* d_out, int out_size, void* d_ws, size_t ws_size,
                              hipStream_t stream) {
  const float* inp = (const float*)d_in[0];
  const float* inp_len = (const float*)d_in[1];
  const float* aspect = (const float*)d_in[2];
  const float* w1 = (const float*)d_in[3];
  const float* b1 = (const float*)d_in[4];
  const float* w2 = (const float*)d_in[5];
  const float* b2 = (const float*)d_in[6];
  float* out = (float*)d_out;

  char* W = (char*)d_ws;
  const size_t MB = 1ull << 20;
  unsigned short* asp_bf = (unsigned short*)(W + 0);        // 8 MB
  unsigned short* inpT   = (unsigned short*)(W + 8 * MB);   // 8 MB
  unsigned short* Gm     = (unsigned short*)(W + 16 * MB);  // 4 MB
  unsigned short* w1bf   = (unsigned short*)(W + 20 * MB);  // 512 KB
  unsigned short* w2bf   = (unsigned short*)(W + 20 * MB + 512 * 1024);
  float*          partial= (float*)(W + 21 * MB);           // 512 KB
  float*          fac    = (float*)(W + 22 * MB);           // 32 KB

  // 1) all prep in one launch
  prep_all<<<5120, 256, 0, stream>>>(inp, aspect, w1, w2,
                                     inpT, partial, asp_bf, w1bf, w2bf);

  // 2) gram (1024 balanced 32x64-tile blocks) + fac (512 blocks)
  gram_fac<<<1536, 256, 0, stream>>>(inpT, partial, aspect, inp_len, Gm, fac);

  // 3) mega: W + FFN1 + FFN2 + norm
  hipFuncSetAttribute((const void*)mega_ffn,
                      hipFuncAttributeMaxDynamicSharedMemorySize, MEGA_SMEM);
  mega_ffn<<<256, 512, MEGA_SMEM, stream>>>(
      asp_bf, Gm, w1bf, w2bf, b1, b2, inp, aspect, fac, inp_len, out);
}